// Round 2
// baseline (968.292 us; speedup 1.0000x reference)
//
#include <hip/hip_runtime.h>
#include <hip/hip_bf16.h>
#include <math.h>

// Problem: B=2, N=2048, D_MODEL=1024, H=16, D_HEAD=64. fp32 in/out,
// bf16 MFMA internal (threshold is bf16-grade: 2% of max|ref|).
#define BATCH 2
#define NSEQ  2048
#define DM    1024
#define NH    16
#define DH    64
#define EPS_N 1e-6f

typedef unsigned short u16;
typedef __attribute__((ext_vector_type(8))) short short8;       // bf16x8 MFMA frag
typedef __attribute__((ext_vector_type(8))) unsigned short u16x8;
typedef __attribute__((ext_vector_type(4))) float f32x4;

__device__ __forceinline__ u16 f2bf(float x) {
  __hip_bfloat16 h = __float2bfloat16(x);          // round-to-nearest-even
  return *reinterpret_cast<u16*>(&h);
}

__device__ __forceinline__ float wave_reduce_max(float x) {
  #pragma unroll
  for (int off = 32; off > 0; off >>= 1) x = fmaxf(x, __shfl_xor(x, off, 64));
  return x;
}
__device__ __forceinline__ float wave_reduce_sum(float x) {
  #pragma unroll
  for (int off = 32; off > 0; off >>= 1) x += __shfl_xor(x, off, 64);
  return x;
}

// ---------------------------------------------------------------------------
// Transpose + fp32->bf16 convert 1024x1024 weights: out[n][k] = bf16(in[k][n]).
// grid (16,16,4), 256 thr.
// ---------------------------------------------------------------------------
__global__ __launch_bounds__(256) void transpose_w(
    const float* __restrict__ w0, const float* __restrict__ w1,
    const float* __restrict__ w2, const float* __restrict__ w3,
    u16* __restrict__ out) {
  const float* in = (blockIdx.z == 0) ? w0 : (blockIdx.z == 1) ? w1
                  : (blockIdx.z == 2) ? w2 : w3;
  u16* o = out + (size_t)blockIdx.z * DM * DM;
  __shared__ u16 T[64][65];
  const int tid = threadIdx.x;
  const int n0 = blockIdx.x * 64, k0 = blockIdx.y * 64;
  #pragma unroll
  for (int i = 0; i < 4; i++) {
    int c = tid + 256 * i, row = c >> 4, col4 = c & 15;
    float4 f = *(const float4*)&in[(size_t)(k0 + row) * DM + n0 + col4 * 4];
    T[row][col4 * 4 + 0] = f2bf(f.x);
    T[row][col4 * 4 + 1] = f2bf(f.y);
    T[row][col4 * 4 + 2] = f2bf(f.z);
    T[row][col4 * 4 + 3] = f2bf(f.w);
  }
  __syncthreads();
  #pragma unroll
  for (int i = 0; i < 2; i++) {
    int c = tid + 256 * i, row = c >> 3, col8 = c & 7;
    u16x8 v;
    #pragma unroll
    for (int e = 0; e < 8; e++) v[e] = T[col8 * 8 + e][row];
    *(u16x8*)&o[(size_t)(n0 + row) * DM + k0 + col8 * 8] = v;
  }
}

// ---------------------------------------------------------------------------
// QKV GEMM: C = X[4096,1024] @ W[1024,1024]. X fp32 (cast to bf16 in staging),
// W pre-transposed bf16 (Bt[n][k]). Output fp32, permuted to [B, H, N, DH].
// grid (16, 64, 3), 256 thr.
// ---------------------------------------------------------------------------
__global__ __launch_bounds__(256) void gemm_qkv(
    const float* __restrict__ X, const u16* __restrict__ WT,
    float* __restrict__ Qo, float* __restrict__ Ko, float* __restrict__ Vo) {
  const u16* Bt = WT + (size_t)blockIdx.z * DM * DM;
  float* Out = (blockIdx.z == 0) ? Qo : (blockIdx.z == 1) ? Ko : Vo;
  __shared__ u16 As[64][72];
  __shared__ u16 Bs[64][72];
  const int tid = threadIdx.x, wave = tid >> 6, lane = tid & 63;
  const int m0 = blockIdx.y * 64, n0 = blockIdx.x * 64;
  const int ml = lane & 15, quad = lane >> 4;

  f32x4 acc[4];
  #pragma unroll
  for (int s = 0; s < 4; s++)
    #pragma unroll
    for (int e = 0; e < 4; e++) acc[s][e] = 0.f;

  for (int k0 = 0; k0 < DM; k0 += 64) {
    u16x8 av[2], bv[2];
    #pragma unroll
    for (int i = 0; i < 2; i++) {
      int c = tid + 256 * i, row = c >> 3, col8 = c & 7;
      const float* src = &X[(size_t)(m0 + row) * DM + k0 + col8 * 8];
      float4 f0 = *(const float4*)(src);
      float4 f1 = *(const float4*)(src + 4);
      av[i][0] = f2bf(f0.x); av[i][1] = f2bf(f0.y);
      av[i][2] = f2bf(f0.z); av[i][3] = f2bf(f0.w);
      av[i][4] = f2bf(f1.x); av[i][5] = f2bf(f1.y);
      av[i][6] = f2bf(f1.z); av[i][7] = f2bf(f1.w);
      bv[i] = *(const u16x8*)&Bt[(size_t)(n0 + row) * DM + k0 + col8 * 8];
    }
    __syncthreads();
    #pragma unroll
    for (int i = 0; i < 2; i++) {
      int c = tid + 256 * i, row = c >> 3, col8 = c & 7;
      *(u16x8*)&As[row][col8 * 8] = av[i];
      *(u16x8*)&Bs[row][col8 * 8] = bv[i];
    }
    __syncthreads();
    #pragma unroll
    for (int kk = 0; kk < 64; kk += 32) {
      short8 af = *(const short8*)&As[wave * 16 + ml][kk + quad * 8];
      #pragma unroll
      for (int s = 0; s < 4; s++) {
        short8 bf = *(const short8*)&Bs[s * 16 + ml][kk + quad * 8];
        acc[s] = __builtin_amdgcn_mfma_f32_16x16x32_bf16(af, bf, acc[s], 0, 0, 0);
      }
    }
  }
  // epilogue: D col=lane&15, row=quad*4+r. permute to [B,H,N,DH]
  const int h = n0 >> 6;
  #pragma unroll
  for (int s = 0; s < 4; s++) {
    #pragma unroll
    for (int r = 0; r < 4; r++) {
      int row = m0 + wave * 16 + quad * 4 + r;       // global token row 0..4095
      int b = row >> 11, tok = row & (NSEQ - 1);
      int d = s * 16 + ml;
      Out[((size_t)(b * NH + h) * NSEQ + tok) * DH + d] = acc[s][r];
    }
  }
}

// ---------------------------------------------------------------------------
// L2 normalize rows of 64 (covers Q then K, contiguous in ws). wave per row.
// ---------------------------------------------------------------------------
__global__ __launch_bounds__(256) void l2norm_rows(float* __restrict__ base) {
  const int wave = threadIdx.x >> 6, lane = threadIdx.x & 63;
  const size_t row = (size_t)blockIdx.x * 4 + wave;
  float* p = base + row * DH;
  float v = p[lane];
  float ss = wave_reduce_sum(v * v);
  p[lane] = v / (sqrtf(ss) + EPS_N);
}

// ---------------------------------------------------------------------------
// Flash attention (online softmax), causal. One block = 16 q-rows of one
// (b,h); one wave = 4 q-rows. K/V tiles (64 keys) staged in LDS.
// Writes V_hat bf16 in [B*N, H*DH] layout. grid (128, 16, 2), 256 thr.
// ---------------------------------------------------------------------------
__global__ __launch_bounds__(256) void flash_attn(
    const float* __restrict__ Q, const float* __restrict__ K,
    const float* __restrict__ V, __hip_bfloat16* __restrict__ vhat) {
  const int tid = threadIdx.x, w = tid >> 6, lane = tid & 63;
  const int hb = blockIdx.y, bb = blockIdx.z;
  const int bh = bb * NH + hb;
  const int qbase = blockIdx.x * 16;
  const float* Qh = Q + (size_t)bh * NSEQ * DH;
  const float* Kh = K + (size_t)bh * NSEQ * DH;
  const float* Vh = V + (size_t)bh * NSEQ * DH;

  __shared__ float Ks[64][65];     // +1 pad: (lane+d)%32 banks, 2-way free
  __shared__ float Vs[64][64];     // read Vs[jj][lane]: bank=lane%32, free
  __shared__ float Qs[4][64][4];   // [wave][d][r], broadcast-read as float4
  __shared__ float Ps[4][64][4];   // [wave][key][r]

  int q_[4];
  float m_[4], l_[4], o_[4], qv[4];
  #pragma unroll
  for (int r = 0; r < 4; r++) {
    q_[r] = qbase + 4 * w + r;
    qv[r] = Qh[(size_t)q_[r] * DH + lane];
    m_[r] = -INFINITY; l_[r] = 0.f; o_[r] = 0.f;
  }
  *(float4*)&Qs[w][lane][0] = make_float4(qv[0], qv[1], qv[2], qv[3]);

  const int ntiles = ((qbase + 15) >> 6) + 1;
  for (int t = 0; t < ntiles; t++) {
    const int j0 = t * 64;
    // prefetch K/V tile to regs before barrier
    float4 kreg[4], vreg[4];
    #pragma unroll
    for (int i = 0; i < 4; i++) {
      int c = tid + 256 * i, row = c >> 4, col4 = c & 15;
      kreg[i] = *(const float4*)&Kh[(size_t)(j0 + row) * DH + col4 * 4];
      vreg[i] = *(const float4*)&Vh[(size_t)(j0 + row) * DH + col4 * 4];
    }
    __syncthreads();
    #pragma unroll
    for (int i = 0; i < 4; i++) {
      int c = tid + 256 * i, row = c >> 4, col4 = c & 15;
      Ks[row][col4 * 4 + 0] = kreg[i].x;
      Ks[row][col4 * 4 + 1] = kreg[i].y;
      Ks[row][col4 * 4 + 2] = kreg[i].z;
      Ks[row][col4 * 4 + 3] = kreg[i].w;
      *(float4*)&Vs[row][col4 * 4] = vreg[i];
    }
    __syncthreads();

    // scores: lane owns key j0+lane; 4 q-rows at once
    float s0 = 0.f, s1 = 0.f, s2 = 0.f, s3 = 0.f;
    #pragma unroll 8
    for (int d = 0; d < 64; d++) {
      float kd = Ks[lane][d];
      float4 q4 = *(const float4*)&Qs[w][d][0];   // wave-uniform broadcast
      s0 += q4.x * kd; s1 += q4.y * kd; s2 += q4.z * kd; s3 += q4.w * kd;
    }
    float s_[4] = {s0, s1, s2, s3};
    const int j = j0 + lane;
    float p_[4], al_[4];
    #pragma unroll
    for (int r = 0; r < 4; r++) {
      float sv = s_[r] * 0.125f;                  // 1/sqrt(64)
      if (j > q_[r]) sv = -INFINITY;              // causal mask
      float tm = wave_reduce_max(sv);
      float nm = fmaxf(m_[r], tm);
      float al = __expf(m_[r] - nm);              // first tile: exp(-inf)=0
      float pv = __expf(sv - nm);
      float psum = wave_reduce_sum(pv);
      l_[r] = l_[r] * al + psum;
      m_[r] = nm; al_[r] = al; p_[r] = pv;
    }
    *(float4*)&Ps[w][lane][0] = make_float4(p_[0], p_[1], p_[2], p_[3]);
    #pragma unroll
    for (int r = 0; r < 4; r++) o_[r] *= al_[r];
    #pragma unroll 8
    for (int jj = 0; jj < 64; jj++) {
      float4 p4 = *(const float4*)&Ps[w][jj][0];  // wave-uniform broadcast
      float vv = Vs[jj][lane];
      o_[0] += p4.x * vv; o_[1] += p4.y * vv; o_[2] += p4.z * vv; o_[3] += p4.w * vv;
    }
  }
  #pragma unroll
  for (int r = 0; r < 4; r++) {
    float res = o_[r] / l_[r];
    vhat[((size_t)(bb * NSEQ + q_[r])) * DM + hb * DH + lane] = __float2bfloat16(res);
  }
}

// ---------------------------------------------------------------------------
// Output projection: out = vhat[4096,1024] @ Wo + bo, fp32 out.
// WoT given transposed bf16. grid (16, 64), 256 thr.
// ---------------------------------------------------------------------------
__global__ __launch_bounds__(256) void gemm_proj(
    const u16* __restrict__ A, const u16* __restrict__ Bt,
    const float* __restrict__ bias, float* __restrict__ out) {
  __shared__ u16 As[64][72];
  __shared__ u16 Bs[64][72];
  const int tid = threadIdx.x, wave = tid >> 6, lane = tid & 63;
  const int m0 = blockIdx.y * 64, n0 = blockIdx.x * 64;
  const int ml = lane & 15, quad = lane >> 4;

  f32x4 acc[4];
  #pragma unroll
  for (int s = 0; s < 4; s++)
    #pragma unroll
    for (int e = 0; e < 4; e++) acc[s][e] = 0.f;

  const int ca = tid, cb = tid + 256;
  const int ra = ca >> 3, c8a = ca & 7, rb = cb >> 3, c8b = cb & 7;

  for (int k0 = 0; k0 < DM; k0 += 64) {
    u16x8 a0 = *(const u16x8*)&A [(size_t)(m0 + ra) * DM + k0 + c8a * 8];
    u16x8 a1 = *(const u16x8*)&A [(size_t)(m0 + rb) * DM + k0 + c8b * 8];
    u16x8 b0 = *(const u16x8*)&Bt[(size_t)(n0 + ra) * DM + k0 + c8a * 8];
    u16x8 b1 = *(const u16x8*)&Bt[(size_t)(n0 + rb) * DM + k0 + c8b * 8];
    __syncthreads();
    *(u16x8*)&As[ra][c8a * 8] = a0;
    *(u16x8*)&As[rb][c8b * 8] = a1;
    *(u16x8*)&Bs[ra][c8a * 8] = b0;
    *(u16x8*)&Bs[rb][c8b * 8] = b1;
    __syncthreads();
    #pragma unroll
    for (int kk = 0; kk < 64; kk += 32) {
      short8 af = *(const short8*)&As[wave * 16 + ml][kk + quad * 8];
      #pragma unroll
      for (int s = 0; s < 4; s++) {
        short8 bf = *(const short8*)&Bs[s * 16 + ml][kk + quad * 8];
        acc[s] = __builtin_amdgcn_mfma_f32_16x16x32_bf16(af, bf, acc[s], 0, 0, 0);
      }
    }
  }
  #pragma unroll
  for (int s = 0; s < 4; s++) {
    int col = n0 + s * 16 + ml;
    float bz = bias[col];
    #pragma unroll
    for (int r = 0; r < 4; r++) {
      int row = m0 + wave * 16 + quad * 4 + r;
      out[(size_t)row * DM + col] = acc[s][r] + bz;
    }
  }
}

// ---------------------------------------------------------------------------
extern "C" void kernel_launch(void* const* d_in, const int* in_sizes, int n_in,
                              void* d_out, int out_size, void* d_ws, size_t ws_size,
                              hipStream_t stream) {
  const float* X  = (const float*)d_in[0];
  const float* Wq = (const float*)d_in[1];
  const float* Wk = (const float*)d_in[2];
  const float* Wv = (const float*)d_in[3];
  const float* Wo = (const float*)d_in[4];
  const float* bo = (const float*)d_in[5];
  float* out = (float*)d_out;

  // ws layout: Q,K,V fp32 [B,H,N,DH] (16 MB each) | vhat bf16 (8 MB) | WT bf16 (8 MB)
  const size_t NE = (size_t)BATCH * NSEQ * DM;   // 4,194,304
  float* Qf = (float*)d_ws;
  float* Kf = Qf + NE;
  float* Vf = Kf + NE;
  __hip_bfloat16* vhat = (__hip_bfloat16*)(Vf + NE);
  u16* WT = (u16*)(vhat + NE);

  transpose_w<<<dim3(16, 16, 4), 256, 0, stream>>>(Wq, Wk, Wv, Wo, WT);
  gemm_qkv<<<dim3(16, 64, 3), 256, 0, stream>>>(X, WT, Qf, Kf, Vf);
  l2norm_rows<<<dim3((2 * BATCH * NH * NSEQ) / 4), 256, 0, stream>>>(Qf); // Q+K contiguous
  flash_attn<<<dim3(NSEQ / 16, NH, BATCH), 256, 0, stream>>>(Qf, Kf, Vf, vhat);
  gemm_proj<<<dim3(16, 64, 1), 256, 0, stream>>>((const u16*)vhat, WT + 3 * (size_t)DM * DM,
                                                 bo, out);
}

// Round 3
// 259.564 us; speedup vs baseline: 3.7305x; 3.7305x over previous
//
#include <hip/hip_runtime.h>
#include <hip/hip_bf16.h>
#include <math.h>

// Problem: B=2, N=2048, D_MODEL=1024, H=16, D_HEAD=64. fp32 in/out,
// bf16 MFMA internal (threshold is bf16-grade: 2% of max|ref|).
#define BATCH 2
#define NSEQ  2048
#define DM    1024
#define NH    16
#define DH    64
#define EPS_N 1e-6f

typedef unsigned short u16;
typedef __attribute__((ext_vector_type(8))) short short8;       // bf16x8 MFMA frag
typedef __attribute__((ext_vector_type(8))) unsigned short u16x8;
typedef __attribute__((ext_vector_type(4))) float f32x4;

__device__ __forceinline__ u16 f2bf(float x) {
  __hip_bfloat16 h = __float2bfloat16(x);          // round-to-nearest-even
  return *reinterpret_cast<u16*>(&h);
}
__device__ __forceinline__ float bf2f(u16 x) {
  unsigned int u = ((unsigned int)x) << 16;
  return *reinterpret_cast<float*>(&u);
}

__device__ __forceinline__ float wave_reduce_sum(float x) {
  #pragma unroll
  for (int off = 32; off > 0; off >>= 1) x += __shfl_xor(x, off, 64);
  return x;
}

// ---------------------------------------------------------------------------
// Transpose + fp32->bf16 convert 1024x1024 weights: out[n][k] = bf16(in[k][n]).
// grid (16,16,4), 256 thr.
// ---------------------------------------------------------------------------
__global__ __launch_bounds__(256) void transpose_w(
    const float* __restrict__ w0, const float* __restrict__ w1,
    const float* __restrict__ w2, const float* __restrict__ w3,
    u16* __restrict__ out) {
  const float* in = (blockIdx.z == 0) ? w0 : (blockIdx.z == 1) ? w1
                  : (blockIdx.z == 2) ? w2 : w3;
  u16* o = out + (size_t)blockIdx.z * DM * DM;
  __shared__ u16 T[64][65];
  const int tid = threadIdx.x;
  const int n0 = blockIdx.x * 64, k0 = blockIdx.y * 64;
  #pragma unroll
  for (int i = 0; i < 4; i++) {
    int c = tid + 256 * i, row = c >> 4, col4 = c & 15;
    float4 f = *(const float4*)&in[(size_t)(k0 + row) * DM + n0 + col4 * 4];
    T[row][col4 * 4 + 0] = f2bf(f.x);
    T[row][col4 * 4 + 1] = f2bf(f.y);
    T[row][col4 * 4 + 2] = f2bf(f.z);
    T[row][col4 * 4 + 3] = f2bf(f.w);
  }
  __syncthreads();
  #pragma unroll
  for (int i = 0; i < 2; i++) {
    int c = tid + 256 * i, row = c >> 3, col8 = c & 7;
    u16x8 v;
    #pragma unroll
    for (int e = 0; e < 8; e++) v[e] = T[col8 * 8 + e][row];
    *(u16x8*)&o[(size_t)(n0 + row) * DM + k0 + col8 * 8] = v;
  }
}

// ---------------------------------------------------------------------------
// QKV GEMM: C = X[4096,1024] @ W[1024,1024]. X fp32 (cast to bf16 in staging),
// W pre-transposed bf16 (Bt[n][k]). Output bf16, permuted to [B, H, N, DH].
// grid (16, 64, 3), 256 thr.
// ---------------------------------------------------------------------------
__global__ __launch_bounds__(256) void gemm_qkv(
    const float* __restrict__ X, const u16* __restrict__ WT,
    u16* __restrict__ Qo, u16* __restrict__ Ko, u16* __restrict__ Vo) {
  const u16* Bt = WT + (size_t)blockIdx.z * DM * DM;
  u16* Out = (blockIdx.z == 0) ? Qo : (blockIdx.z == 1) ? Ko : Vo;
  __shared__ u16 As[64][72];
  __shared__ u16 Bs[64][72];
  const int tid = threadIdx.x, wave = tid >> 6, lane = tid & 63;
  const int m0 = blockIdx.y * 64, n0 = blockIdx.x * 64;
  const int ml = lane & 15, quad = lane >> 4;

  f32x4 acc[4];
  #pragma unroll
  for (int s = 0; s < 4; s++)
    #pragma unroll
    for (int e = 0; e < 4; e++) acc[s][e] = 0.f;

  for (int k0 = 0; k0 < DM; k0 += 64) {
    u16x8 av[2], bv[2];
    #pragma unroll
    for (int i = 0; i < 2; i++) {
      int c = tid + 256 * i, row = c >> 3, col8 = c & 7;
      const float* src = &X[(size_t)(m0 + row) * DM + k0 + col8 * 8];
      float4 f0 = *(const float4*)(src);
      float4 f1 = *(const float4*)(src + 4);
      av[i][0] = f2bf(f0.x); av[i][1] = f2bf(f0.y);
      av[i][2] = f2bf(f0.z); av[i][3] = f2bf(f0.w);
      av[i][4] = f2bf(f1.x); av[i][5] = f2bf(f1.y);
      av[i][6] = f2bf(f1.z); av[i][7] = f2bf(f1.w);
      bv[i] = *(const u16x8*)&Bt[(size_t)(n0 + row) * DM + k0 + col8 * 8];
    }
    __syncthreads();
    #pragma unroll
    for (int i = 0; i < 2; i++) {
      int c = tid + 256 * i, row = c >> 3, col8 = c & 7;
      *(u16x8*)&As[row][col8 * 8] = av[i];
      *(u16x8*)&Bs[row][col8 * 8] = bv[i];
    }
    __syncthreads();
    #pragma unroll
    for (int kk = 0; kk < 64; kk += 32) {
      short8 af = *(const short8*)&As[wave * 16 + ml][kk + quad * 8];
      #pragma unroll
      for (int s = 0; s < 4; s++) {
        short8 bf = *(const short8*)&Bs[s * 16 + ml][kk + quad * 8];
        acc[s] = __builtin_amdgcn_mfma_f32_16x16x32_bf16(af, bf, acc[s], 0, 0, 0);
      }
    }
  }
  // epilogue: D col=lane&15, row=quad*4+r. permute to [B,H,N,DH], bf16
  const int h = n0 >> 6;
  #pragma unroll
  for (int s = 0; s < 4; s++) {
    #pragma unroll
    for (int r = 0; r < 4; r++) {
      int row = m0 + wave * 16 + quad * 4 + r;       // global token row 0..4095
      int b = row >> 11, tok = row & (NSEQ - 1);
      int d = s * 16 + ml;
      Out[((size_t)(b * NH + h) * NSEQ + tok) * DH + d] = f2bf(acc[s][r]);
    }
  }
}

// ---------------------------------------------------------------------------
// L2 normalize bf16 rows of 64 in place (Qb then Kb, contiguous). Q rows also
// get the 1/sqrt(DH)=1/8 softmax scale folded in (exact: power of two).
// wave per row, grid 2*B*H*N/4 blocks.
// ---------------------------------------------------------------------------
__global__ __launch_bounds__(256) void l2norm_rows(u16* __restrict__ base) {
  const int wave = threadIdx.x >> 6, lane = threadIdx.x & 63;
  const size_t row = (size_t)blockIdx.x * 4 + wave;
  u16* p = base + row * DH;
  float v = bf2f(p[lane]);
  float ss = wave_reduce_sum(v * v);
  const bool isQ = row < (size_t)BATCH * NH * NSEQ;
  float sc = (isQ ? 0.125f : 1.0f) / (sqrtf(ss) + EPS_N);
  p[lane] = f2bf(v * sc);
}

// ---------------------------------------------------------------------------
// MFMA flash attention, causal, NO online max: Q,K are unit vectors scaled by
// 1/8 -> |score| <= 0.125, exp can't overflow, so softmax uses fixed max=0.
// Block = 64 q-rows of one (b,h); wave w owns q rows q0+16w..+15.
// Per 64-key tile: S = Q·K^T via 8 mfma_16x16x32_bf16, exp in C-layout,
// P -> per-wave LDS (C-layout -> A-layout transform), PV via 8 MFMAs.
// l (denominator) = per-lane partial, one shfl-reduce at the end.
// grid (32, 16, 2), 256 thr.
// ---------------------------------------------------------------------------
__global__ __launch_bounds__(256) void flash_attn(
    const u16* __restrict__ Qb, const u16* __restrict__ Kb,
    const u16* __restrict__ Vb, u16* __restrict__ vhat) {
  const int tid = threadIdx.x, w = tid >> 6, lane = tid & 63;
  const int ml = lane & 15, quad = lane >> 4;
  const int qb = blockIdx.x, hb = blockIdx.y, bb = blockIdx.z;
  const int bh = bb * NH + hb, q0 = qb * 64;
  const u16* Qh = Qb + (size_t)bh * NSEQ * DH;
  const u16* Kh = Kb + (size_t)bh * NSEQ * DH;
  const u16* Vh = Vb + (size_t)bh * NSEQ * DH;

  // row stride 72 u16 = 144 B: 16B-aligned rows (ds_read_b128), 36 dwords
  // -> frag-read bank pattern is 2-way max (free, m136).
  __shared__ u16 Ks [64][72];      // K[key][d]
  __shared__ u16 VsT[64][72];      // V^T[d][key]
  __shared__ u16 Ps [4][16][72];   // per-wave P[q][key] (C->A transform)

  // Q A-frags, direct from global: A[m=ml][k=quad*8+j], chunks c: d=c*32+...
  short8 aq[2];
  #pragma unroll
  for (int c = 0; c < 2; c++)
    aq[c] = *(const short8*)&Qh[(size_t)(q0 + w * 16 + ml) * DH + c * 32 + quad * 8];

  f32x4 oacc[4];
  #pragma unroll
  for (int n = 0; n < 4; n++)
    #pragma unroll
    for (int e = 0; e < 4; e++) oacc[n][e] = 0.f;
  float l_[4] = {0.f, 0.f, 0.f, 0.f};

  for (int t = 0; t <= qb; t++) {
    const int j0 = t * 64;
    // prefetch K/V (thread -> key=lane, d8 = w + 4i)
    u16x8 kreg[2], vreg[2];
    #pragma unroll
    for (int i = 0; i < 2; i++) {
      int d8 = w + 4 * i;
      kreg[i] = *(const u16x8*)&Kh[(size_t)(j0 + lane) * DH + d8 * 8];
      vreg[i] = *(const u16x8*)&Vh[(size_t)(j0 + lane) * DH + d8 * 8];
    }
    __syncthreads();                       // all waves done with prev tile
    #pragma unroll
    for (int i = 0; i < 2; i++) {
      int d8 = w + 4 * i;
      *(u16x8*)&Ks[lane][d8 * 8] = kreg[i];
      #pragma unroll
      for (int e = 0; e < 8; e++) VsT[d8 * 8 + e][lane] = vreg[i][e];
    }
    __syncthreads();

    // S = Q · K^T : B-frag = K[key=n*16+ml][d=c*32+quad*8+j]
    f32x4 sacc[4];
    #pragma unroll
    for (int n = 0; n < 4; n++)
      #pragma unroll
      for (int e = 0; e < 4; e++) sacc[n][e] = 0.f;
    #pragma unroll
    for (int c = 0; c < 2; c++) {
      #pragma unroll
      for (int n = 0; n < 4; n++) {
        short8 bf = *(const short8*)&Ks[n * 16 + ml][c * 32 + quad * 8];
        sacc[n] = __builtin_amdgcn_mfma_f32_16x16x32_bf16(aq[c], bf, sacc[n], 0, 0, 0);
      }
    }

    // p = exp(s) (fixed max = 0; masked -> 0). C-layout: col=ml (key), row=quad*4+r (q)
    float p[4][4];
    if (t == qb) {
      #pragma unroll
      for (int n = 0; n < 4; n++) {
        int j = j0 + n * 16 + ml;
        #pragma unroll
        for (int r = 0; r < 4; r++) {
          int q = q0 + w * 16 + quad * 4 + r;
          float e = __expf(sacc[n][r]);
          p[n][r] = (j > q) ? 0.f : e;
        }
      }
    } else {
      #pragma unroll
      for (int n = 0; n < 4; n++)
        #pragma unroll
        for (int r = 0; r < 4; r++) p[n][r] = __expf(sacc[n][r]);
    }
    #pragma unroll
    for (int n = 0; n < 4; n++)
      #pragma unroll
      for (int r = 0; r < 4; r++) l_[r] += p[n][r];

    // P -> per-wave LDS (no block barrier needed; same-wave lgkmcnt ordering)
    #pragma unroll
    for (int n = 0; n < 4; n++)
      #pragma unroll
      for (int r = 0; r < 4; r++)
        Ps[w][quad * 4 + r][n * 16 + ml] = f2bf(p[n][r]);

    // O += P · V : A-frag = P[q=ml][key=c*32+quad*8+j], B-frag = V^T[d=n*16+ml][key]
    #pragma unroll
    for (int c = 0; c < 2; c++) {
      short8 ap = *(const short8*)&Ps[w][ml][c * 32 + quad * 8];
      #pragma unroll
      for (int n = 0; n < 4; n++) {
        short8 bv = *(const short8*)&VsT[n * 16 + ml][c * 32 + quad * 8];
        oacc[n] = __builtin_amdgcn_mfma_f32_16x16x32_bf16(ap, bv, oacc[n], 0, 0, 0);
      }
    }
  }

  // epilogue: row sums live split across the 16 lanes of each quad group
  #pragma unroll
  for (int r = 0; r < 4; r++) {
    float lv = l_[r];
    lv += __shfl_xor(lv, 1, 64);
    lv += __shfl_xor(lv, 2, 64);
    lv += __shfl_xor(lv, 4, 64);
    lv += __shfl_xor(lv, 8, 64);
    float inv = 1.f / lv;
    int q = q0 + w * 16 + quad * 4 + r;
    #pragma unroll
    for (int n = 0; n < 4; n++) {
      vhat[((size_t)(bb * NSEQ + q)) * DM + hb * DH + n * 16 + ml] =
          f2bf(oacc[n][r] * inv);
    }
  }
}

// ---------------------------------------------------------------------------
// Output projection: out = vhat[4096,1024] @ Wo + bo, fp32 out.
// WoT given transposed bf16. grid (16, 64), 256 thr.
// ---------------------------------------------------------------------------
__global__ __launch_bounds__(256) void gemm_proj(
    const u16* __restrict__ A, const u16* __restrict__ Bt,
    const float* __restrict__ bias, float* __restrict__ out) {
  __shared__ u16 As[64][72];
  __shared__ u16 Bs[64][72];
  const int tid = threadIdx.x, wave = tid >> 6, lane = tid & 63;
  const int m0 = blockIdx.y * 64, n0 = blockIdx.x * 64;
  const int ml = lane & 15, quad = lane >> 4;

  f32x4 acc[4];
  #pragma unroll
  for (int s = 0; s < 4; s++)
    #pragma unroll
    for (int e = 0; e < 4; e++) acc[s][e] = 0.f;

  const int ca = tid, cb = tid + 256;
  const int ra = ca >> 3, c8a = ca & 7, rb = cb >> 3, c8b = cb & 7;

  for (int k0 = 0; k0 < DM; k0 += 64) {
    u16x8 a0 = *(const u16x8*)&A [(size_t)(m0 + ra) * DM + k0 + c8a * 8];
    u16x8 a1 = *(const u16x8*)&A [(size_t)(m0 + rb) * DM + k0 + c8b * 8];
    u16x8 b0 = *(const u16x8*)&Bt[(size_t)(n0 + ra) * DM + k0 + c8a * 8];
    u16x8 b1 = *(const u16x8*)&Bt[(size_t)(n0 + rb) * DM + k0 + c8b * 8];
    __syncthreads();
    *(u16x8*)&As[ra][c8a * 8] = a0;
    *(u16x8*)&As[rb][c8b * 8] = a1;
    *(u16x8*)&Bs[ra][c8a * 8] = b0;
    *(u16x8*)&Bs[rb][c8b * 8] = b1;
    __syncthreads();
    #pragma unroll
    for (int kk = 0; kk < 64; kk += 32) {
      short8 af = *(const short8*)&As[wave * 16 + ml][kk + quad * 8];
      #pragma unroll
      for (int s = 0; s < 4; s++) {
        short8 bf = *(const short8*)&Bs[s * 16 + ml][kk + quad * 8];
        acc[s] = __builtin_amdgcn_mfma_f32_16x16x32_bf16(af, bf, acc[s], 0, 0, 0);
      }
    }
  }
  #pragma unroll
  for (int s = 0; s < 4; s++) {
    int col = n0 + s * 16 + ml;
    float bz = bias[col];
    #pragma unroll
    for (int r = 0; r < 4; r++) {
      int row = m0 + wave * 16 + quad * 4 + r;
      out[(size_t)row * DM + col] = acc[s][r] + bz;
    }
  }
}

// ---------------------------------------------------------------------------
extern "C" void kernel_launch(void* const* d_in, const int* in_sizes, int n_in,
                              void* d_out, int out_size, void* d_ws, size_t ws_size,
                              hipStream_t stream) {
  const float* X  = (const float*)d_in[0];
  const float* Wq = (const float*)d_in[1];
  const float* Wk = (const float*)d_in[2];
  const float* Wv = (const float*)d_in[3];
  const float* Wo = (const float*)d_in[4];
  const float* bo = (const float*)d_in[5];
  float* out = (float*)d_out;

  // ws layout (all bf16): Qb | Kb | Vb | vhat (8 MB each, [B,H,N,DH] for QKV,
  // [B,N,H*DH] for vhat) | WT (8 MB, 4x transposed weights) = 40 MB
  const size_t NE = (size_t)BATCH * NSEQ * DM;   // 4,194,304
  u16* Qb   = (u16*)d_ws;
  u16* Kb   = Qb + NE;
  u16* Vb   = Kb + NE;
  u16* vhat = Vb + NE;
  u16* WT   = vhat + NE;

  transpose_w<<<dim3(16, 16, 4), 256, 0, stream>>>(Wq, Wk, Wv, Wo, WT);
  gemm_qkv<<<dim3(16, 64, 3), 256, 0, stream>>>(X, WT, Qb, Kb, Vb);
  l2norm_rows<<<dim3((2 * BATCH * NH * NSEQ) / 4), 256, 0, stream>>>(Qb); // Q+K contiguous
  flash_attn<<<dim3(NSEQ / 64, NH, BATCH), 256, 0, stream>>>(Qb, Kb, Vb, vhat);
  gemm_proj<<<dim3(16, 64, 1), 256, 0, stream>>>(vhat, WT + 3 * (size_t)DM * DM,
                                                 bo, out);
}

// Round 5
// 228.803 us; speedup vs baseline: 4.2320x; 1.1344x over previous
//
#include <hip/hip_runtime.h>
#include <hip/hip_bf16.h>
#include <math.h>

// Problem: B=2, N=2048, D_MODEL=1024, H=16, D_HEAD=64. fp32 in/out,
// bf16 MFMA internal (threshold is bf16-grade: 2% of max|ref|).
#define BATCH 2
#define NSEQ  2048
#define DM    1024
#define NH    16
#define DH    64
#define EPS_N 1e-6f

typedef unsigned short u16;
typedef __attribute__((ext_vector_type(8))) short short8;       // bf16x8 MFMA frag
typedef __attribute__((ext_vector_type(8))) unsigned short u16x8;
typedef __attribute__((ext_vector_type(4))) unsigned short u16x4;
typedef __attribute__((ext_vector_type(4))) float f32x4;

__device__ __forceinline__ u16 f2bf(float x) {
  __hip_bfloat16 h = __float2bfloat16(x);          // round-to-nearest-even
  return *reinterpret_cast<u16*>(&h);
}
__device__ __forceinline__ float bf2f(u16 x) {
  unsigned int u = ((unsigned int)x) << 16;
  return *reinterpret_cast<float*>(&u);
}

__device__ __forceinline__ float wave_reduce_sum(float x) {
  #pragma unroll
  for (int off = 32; off > 0; off >>= 1) x += __shfl_xor(x, off, 64);
  return x;
}

// async 16B global->LDS (lane i lands at lds_base + 16*i)
__device__ __forceinline__ void gl_lds16(const u16* g, u16* lds_base) {
  __builtin_amdgcn_global_load_lds(
      (__attribute__((address_space(1))) void*)g,
      (__attribute__((address_space(3))) void*)lds_base, 16, 0, 0);
}

// ---------------------------------------------------------------------------
// Cast X fp32 -> bf16 (for global_load_lds staging). grid 2048, 256 thr.
// ---------------------------------------------------------------------------
__global__ __launch_bounds__(256) void cast_x(
    const float* __restrict__ X, u16* __restrict__ Xb) {
  size_t base = ((size_t)blockIdx.x * 256 + threadIdx.x) * 8;
  float4 f0 = *(const float4*)&X[base];
  float4 f1 = *(const float4*)&X[base + 4];
  u16x8 v;
  v[0] = f2bf(f0.x); v[1] = f2bf(f0.y); v[2] = f2bf(f0.z); v[3] = f2bf(f0.w);
  v[4] = f2bf(f1.x); v[5] = f2bf(f1.y); v[6] = f2bf(f1.z); v[7] = f2bf(f1.w);
  *(u16x8*)&Xb[base] = v;
}

// ---------------------------------------------------------------------------
// Transpose + fp32->bf16 convert 1024x1024 weights: out[n][k] = bf16(in[k][n]).
// grid (16,16,4), 256 thr.
// ---------------------------------------------------------------------------
__global__ __launch_bounds__(256) void transpose_w(
    const float* __restrict__ w0, const float* __restrict__ w1,
    const float* __restrict__ w2, const float* __restrict__ w3,
    u16* __restrict__ out) {
  const float* in = (blockIdx.z == 0) ? w0 : (blockIdx.z == 1) ? w1
                  : (blockIdx.z == 2) ? w2 : w3;
  u16* o = out + (size_t)blockIdx.z * DM * DM;
  __shared__ u16 T[64][65];
  const int tid = threadIdx.x;
  const int n0 = blockIdx.x * 64, k0 = blockIdx.y * 64;
  #pragma unroll
  for (int i = 0; i < 4; i++) {
    int c = tid + 256 * i, row = c >> 4, col4 = c & 15;
    float4 f = *(const float4*)&in[(size_t)(k0 + row) * DM + n0 + col4 * 4];
    T[row][col4 * 4 + 0] = f2bf(f.x);
    T[row][col4 * 4 + 1] = f2bf(f.y);
    T[row][col4 * 4 + 2] = f2bf(f.z);
    T[row][col4 * 4 + 3] = f2bf(f.w);
  }
  __syncthreads();
  #pragma unroll
  for (int i = 0; i < 2; i++) {
    int c = tid + 256 * i, row = c >> 3, col8 = c & 7;
    u16x8 v;
    #pragma unroll
    for (int e = 0; e < 8; e++) v[e] = T[col8 * 8 + e][row];
    *(u16x8*)&o[(size_t)(n0 + row) * DM + k0 + col8 * 8] = v;
  }
}

// ===========================================================================
// m97-style 128x128 GEMM mainloop (BK=64, global_load_lds 16B, XOR-swizzled
// LDS chunks). A[m][k], Bt[n][k] both bf16. 256 thr, 4 waves in 2x2 (wm,wn).
// Each wave computes 64x64 = 4x4 16x16 C tiles. Shared by qkv and proj via
// a macro to keep epilogues separate.
// LDS: row r (128 B) holds global chunk g at position g^(r&7) (XOR swizzle).
// ===========================================================================
#define GEMM128_MAINLOOP(Aptr, Btptr)                                          \
  __shared__ u16 As[128 * 64];                                                 \
  __shared__ u16 Bs[128 * 64];                                                 \
  const int tid = threadIdx.x, w = tid >> 6, lane = tid & 63;                  \
  const int ml = lane & 15, quad = lane >> 4;                                  \
  const int m0 = blockIdx.y * 128, n0 = blockIdx.x * 128;                      \
  const int wm = w & 1, wn = w >> 1;                                           \
  const int srow = lane >> 3;                 /* 0..7 within 8-row slab */     \
  const int scol = ((lane & 7) ^ srow) * 8;   /* swizzled global chunk */      \
  f32x4 acc[4][4];                                                             \
  _Pragma("unroll") for (int mi = 0; mi < 4; mi++)                             \
    _Pragma("unroll") for (int ni = 0; ni < 4; ni++)                           \
      _Pragma("unroll") for (int e = 0; e < 4; e++) acc[mi][ni][e] = 0.f;      \
  for (int k0 = 0; k0 < DM; k0 += 64) {                                        \
    __syncthreads();                                                           \
    _Pragma("unroll") for (int L = 0; L < 4; L++) {                            \
      int I = w * 4 + L;                                                       \
      gl_lds16(Aptr  + (size_t)(m0 + I * 8 + srow) * DM + k0 + scol,           \
               As + I * 512);                                                  \
      gl_lds16(Btptr + (size_t)(n0 + I * 8 + srow) * DM + k0 + scol,           \
               Bs + I * 512);                                                  \
    }                                                                          \
    __syncthreads();                                                           \
    _Pragma("unroll") for (int kk = 0; kk < 64; kk += 32) {                    \
      const int kc = kk >> 3;                 /* chunk base: 0 or 4 */         \
      short8 am[4], bn[4];                                                     \
      _Pragma("unroll") for (int i = 0; i < 4; i++) {                          \
        int ra = wm * 64 + i * 16 + ml;                                        \
        int rb = wn * 64 + i * 16 + ml;                                        \
        am[i] = *(const short8*)&As[ra * 64 + (((quad + kc) ^ (ra & 7)) * 8)]; \
        bn[i] = *(const short8*)&Bs[rb * 64 + (((quad + kc) ^ (rb & 7)) * 8)]; \
      }                                                                        \
      _Pragma("unroll") for (int mi = 0; mi < 4; mi++)                         \
        _Pragma("unroll") for (int ni = 0; ni < 4; ni++)                       \
          acc[mi][ni] = __builtin_amdgcn_mfma_f32_16x16x32_bf16(               \
              am[mi], bn[ni], acc[mi][ni], 0, 0, 0);                           \
    }                                                                          \
  }

// ---------------------------------------------------------------------------
// QKV GEMM: Xb[4096][1024] bf16 @ W (WT[n][k] bf16). z selects Q/K/V.
// Q,K -> [B,H,N,DH] bf16;  V -> transposed [B,H,DH,N] bf16 (packed 8B stores).
// grid (8, 32, 3), 256 thr.
// ---------------------------------------------------------------------------
__global__ __launch_bounds__(256) void gemm_qkv128(
    const u16* __restrict__ Xb, const u16* __restrict__ WT,
    u16* __restrict__ Qo, u16* __restrict__ Ko, u16* __restrict__ Vt) {
  const u16* Bt = WT + (size_t)blockIdx.z * DM * DM;
  GEMM128_MAINLOOP(Xb, Bt)
  const int z = blockIdx.z;
  u16* OutQK = (z == 0) ? Qo : Ko;
  #pragma unroll
  for (int mi = 0; mi < 4; mi++) {
    int mrow0 = m0 + wm * 64 + mi * 16 + quad * 4;   // 4-aligned token row
    int b = mrow0 >> 11, tok0 = mrow0 & (NSEQ - 1);
    #pragma unroll
    for (int ni = 0; ni < 4; ni++) {
      int n = n0 + wn * 64 + ni * 16 + ml;
      int h = n >> 6, d = n & 63;
      if (z < 2) {
        #pragma unroll
        for (int r = 0; r < 4; r++)
          OutQK[((size_t)(b * NH + h) * NSEQ + tok0 + r) * DH + d] =
              f2bf(acc[mi][ni][r]);
      } else {
        u16x4 pk;
        #pragma unroll
        for (int r = 0; r < 4; r++) pk[r] = f2bf(acc[mi][ni][r]);
        *(u16x4*)&Vt[((size_t)(b * NH + h) * DH + d) * NSEQ + tok0] = pk;
      }
    }
  }
}

// ---------------------------------------------------------------------------
// Output projection: out = vhat[4096][1024] @ Wo + bo, fp32 out.
// grid (8, 32), 256 thr.
// ---------------------------------------------------------------------------
__global__ __launch_bounds__(256) void gemm_proj128(
    const u16* __restrict__ A, const u16* __restrict__ BtW,
    const float* __restrict__ bias, float* __restrict__ out) {
  GEMM128_MAINLOOP(A, BtW)
  #pragma unroll
  for (int ni = 0; ni < 4; ni++) {
    int n = n0 + wn * 64 + ni * 16 + ml;
    float bz = bias[n];
    #pragma unroll
    for (int mi = 0; mi < 4; mi++) {
      int mrow0 = m0 + wm * 64 + mi * 16 + quad * 4;
      #pragma unroll
      for (int r = 0; r < 4; r++)
        out[(size_t)(mrow0 + r) * DM + n] = acc[mi][ni][r] + bz;
    }
  }
}

// ---------------------------------------------------------------------------
// L2 normalize bf16 rows of 64 in place (Qb then Kb, contiguous). Q rows also
// get the 1/sqrt(DH)=1/8 softmax scale folded in (exact: power of two).
// wave per row, grid 2*B*H*N/4 blocks.
// ---------------------------------------------------------------------------
__global__ __launch_bounds__(256) void l2norm_rows(u16* __restrict__ base) {
  const int wave = threadIdx.x >> 6, lane = threadIdx.x & 63;
  const size_t row = (size_t)blockIdx.x * 4 + wave;
  u16* p = base + row * DH;
  float v = bf2f(p[lane]);
  float ss = wave_reduce_sum(v * v);
  const bool isQ = row < (size_t)BATCH * NH * NSEQ;
  float sc = (isQ ? 0.125f : 1.0f) / (sqrtf(ss) + EPS_N);
  p[lane] = f2bf(v * sc);
}

// ---------------------------------------------------------------------------
// MFMA flash attention, causal, NO online max (|score|<=0.125 by L2 norm).
// Load-balanced: block x processes q-block pair {x, 31-x} -> every block does
// exactly 33 tile-iters. Block = 64 q-rows/phase, wave = 16 q-rows.
// V comes pre-transposed from gemm_qkv (Vt[b,h,d,n]) -> vectorized staging.
// grid (16, 16, 2), 256 thr.
// ---------------------------------------------------------------------------
__global__ __launch_bounds__(256) void flash_attn(
    const u16* __restrict__ Qb, const u16* __restrict__ Kb,
    const u16* __restrict__ Vt, u16* __restrict__ vhat) {
  const int tid = threadIdx.x, w = tid >> 6, lane = tid & 63;
  const int ml = lane & 15, quad = lane >> 4;
  const int hb = blockIdx.y, bb = blockIdx.z;
  const int bh = bb * NH + hb;
  const u16* Qh = Qb + (size_t)bh * NSEQ * DH;
  const u16* Kh = Kb + (size_t)bh * NSEQ * DH;
  const u16* Vth = Vt + (size_t)bh * DH * NSEQ;

  // row stride 72 u16 = 144 B: 16B-aligned rows, 36-dword stride -> frag-read
  // bank pattern is 2-way max (free, m136).
  __shared__ u16 Ks [64][72];      // K[key][d]
  __shared__ u16 VsT[64][72];      // V^T[d][key]
  __shared__ u16 Ps [4][16][72];   // per-wave P[q][key] (C->A transform)

  const int vd = tid >> 2, vc = tid & 3;   // V^T staging: row d, chunks vc,vc+4

  for (int ph = 0; ph < 2; ph++) {
    const int qb = ph ? (31 - (int)blockIdx.x) : (int)blockIdx.x;
    const int q0 = qb * 64;

    // Q A-frags, direct from global: A[m=ml][k=quad*8+j]
    short8 aq[2];
    #pragma unroll
    for (int c = 0; c < 2; c++)
      aq[c] = *(const short8*)&Qh[(size_t)(q0 + w * 16 + ml) * DH + c * 32 + quad * 8];

    f32x4 oacc[4];
    #pragma unroll
    for (int n = 0; n < 4; n++)
      #pragma unroll
      for (int e = 0; e < 4; e++) oacc[n][e] = 0.f;
    float l_[4] = {0.f, 0.f, 0.f, 0.f};

    for (int t = 0; t <= qb; t++) {
      const int j0 = t * 64;
      // prefetch K (key=lane, chunks w, w+4) and V^T (row vd, chunks vc, vc+4)
      u16x8 kreg[2], vreg[2];
      #pragma unroll
      for (int i = 0; i < 2; i++) {
        kreg[i] = *(const u16x8*)&Kh[(size_t)(j0 + lane) * DH + (w + 4 * i) * 8];
        vreg[i] = *(const u16x8*)&Vth[(size_t)vd * NSEQ + j0 + (vc + 4 * i) * 8];
      }
      __syncthreads();                       // all waves done with prev tile
      #pragma unroll
      for (int i = 0; i < 2; i++) {
        *(u16x8*)&Ks[lane][(w + 4 * i) * 8] = kreg[i];
        *(u16x8*)&VsT[vd][(vc + 4 * i) * 8] = vreg[i];
      }
      __syncthreads();

      // S = Q · K^T : B-frag = K[key=n*16+ml][d=c*32+quad*8+j]
      f32x4 sacc[4];
      #pragma unroll
      for (int n = 0; n < 4; n++)
        #pragma unroll
        for (int e = 0; e < 4; e++) sacc[n][e] = 0.f;
      #pragma unroll
      for (int c = 0; c < 2; c++) {
        #pragma unroll
        for (int n = 0; n < 4; n++) {
          short8 bf = *(const short8*)&Ks[n * 16 + ml][c * 32 + quad * 8];
          sacc[n] = __builtin_amdgcn_mfma_f32_16x16x32_bf16(aq[c], bf, sacc[n], 0, 0, 0);
        }
      }

      // p = exp(s) (fixed max=0; masked -> 0). C-layout: col=ml(key), row=quad*4+r(q)
      float p[4][4];
      if (t == qb) {
        #pragma unroll
        for (int n = 0; n < 4; n++) {
          int j = j0 + n * 16 + ml;
          #pragma unroll
          for (int r = 0; r < 4; r++) {
            int q = q0 + w * 16 + quad * 4 + r;
            float e = __expf(sacc[n][r]);
            p[n][r] = (j > q) ? 0.f : e;
          }
        }
      } else {
        #pragma unroll
        for (int n = 0; n < 4; n++)
          #pragma unroll
          for (int r = 0; r < 4; r++) p[n][r] = __expf(sacc[n][r]);
      }
      #pragma unroll
      for (int n = 0; n < 4; n++)
        #pragma unroll
        for (int r = 0; r < 4; r++) l_[r] += p[n][r];

      // P -> per-wave LDS (no block barrier needed; same-wave lgkmcnt ordering)
      #pragma unroll
      for (int n = 0; n < 4; n++)
        #pragma unroll
        for (int r = 0; r < 4; r++)
          Ps[w][quad * 4 + r][n * 16 + ml] = f2bf(p[n][r]);

      // O += P · V : A-frag = P[q=ml][key], B-frag = V^T[d=n*16+ml][key]
      #pragma unroll
      for (int c = 0; c < 2; c++) {
        short8 ap = *(const short8*)&Ps[w][ml][c * 32 + quad * 8];
        #pragma unroll
        for (int n = 0; n < 4; n++) {
          short8 bv = *(const short8*)&VsT[n * 16 + ml][c * 32 + quad * 8];
          oacc[n] = __builtin_amdgcn_mfma_f32_16x16x32_bf16(ap, bv, oacc[n], 0, 0, 0);
        }
      }
    }

    // epilogue: row sums live split across the 16 lanes of each quad group
    #pragma unroll
    for (int r = 0; r < 4; r++) {
      float lv = l_[r];
      lv += __shfl_xor(lv, 1, 64);
      lv += __shfl_xor(lv, 2, 64);
      lv += __shfl_xor(lv, 4, 64);
      lv += __shfl_xor(lv, 8, 64);
      float inv = 1.f / lv;
      int q = q0 + w * 16 + quad * 4 + r;
      #pragma unroll
      for (int n = 0; n < 4; n++) {
        vhat[((size_t)(bb * NSEQ + q)) * DM + hb * DH + n * 16 + ml] =
            f2bf(oacc[n][r] * inv);
      }
    }
  }
}

// ---------------------------------------------------------------------------
extern "C" void kernel_launch(void* const* d_in, const int* in_sizes, int n_in,
                              void* d_out, int out_size, void* d_ws, size_t ws_size,
                              hipStream_t stream) {
  const float* X  = (const float*)d_in[0];
  const float* Wq = (const float*)d_in[1];
  const float* Wk = (const float*)d_in[2];
  const float* Wv = (const float*)d_in[3];
  const float* Wo = (const float*)d_in[4];
  const float* bo = (const float*)d_in[5];
  float* out = (float*)d_out;

  // ws (all bf16, 8 MB each): Qb | Kb | Vt[B,H,DH,N] | {Xb then vhat, aliased:
  // Xb dead after gemm_qkv, vhat born in flash} | WT (4 transposed weights,
  // 8 MB total) = 40 MB
  const size_t NE = (size_t)BATCH * NSEQ * DM;   // 4,194,304
  u16* Qb   = (u16*)d_ws;
  u16* Kb   = Qb + NE;
  u16* Vt   = Kb + NE;
  u16* XbVh = Vt + NE;                           // Xb / vhat (disjoint lifetimes)
  u16* WT   = XbVh + NE;

  cast_x     <<<dim3(2048),       256, 0, stream>>>(X, XbVh);
  transpose_w<<<dim3(16, 16, 4),  256, 0, stream>>>(Wq, Wk, Wv, Wo, WT);
  gemm_qkv128<<<dim3(8, 32, 3),   256, 0, stream>>>(XbVh, WT, Qb, Kb, Vt);
  l2norm_rows<<<dim3((2 * BATCH * NH * NSEQ) / 4), 256, 0, stream>>>(Qb);
  flash_attn <<<dim3(16, 16, 2),  256, 0, stream>>>(Qb, Kb, Vt, XbVh);
  gemm_proj128<<<dim3(8, 32, 1),  256, 0, stream>>>(XbVh, WT + 3 * (size_t)DM * DM,
                                                    bo, out);
}

// Round 6
// 203.909 us; speedup vs baseline: 4.7487x; 1.1221x over previous
//
#include <hip/hip_runtime.h>
#include <hip/hip_bf16.h>
#include <math.h>

// Problem: B=2, N=2048, D_MODEL=1024, H=16, D_HEAD=64. fp32 in/out,
// bf16 MFMA internal (threshold is bf16-grade: 2% of max|ref|).
#define BATCH 2
#define NSEQ  2048
#define DM    1024
#define NH    16
#define DH    64
#define EPS_N 1e-6f

typedef unsigned short u16;
typedef __attribute__((ext_vector_type(8))) short short8;       // bf16x8 MFMA frag
typedef __attribute__((ext_vector_type(8))) unsigned short u16x8;
typedef __attribute__((ext_vector_type(4))) unsigned short u16x4;
typedef __attribute__((ext_vector_type(4))) float f32x4;

__device__ __forceinline__ u16 f2bf(float x) {
  __hip_bfloat16 h = __float2bfloat16(x);          // round-to-nearest-even
  return *reinterpret_cast<u16*>(&h);
}

// async 16B global->LDS (lane i lands at lds_base + 16*i)
__device__ __forceinline__ void gl_lds16(const u16* g, u16* lds_base) {
  __builtin_amdgcn_global_load_lds(
      (__attribute__((address_space(1))) void*)g,
      (__attribute__((address_space(3))) void*)lds_base, 16, 0, 0);
}

// ---------------------------------------------------------------------------
// Prep: blocks 0..1023 transpose+cast the 4 weight matrices (out[n][k] =
// bf16(in[k][n])); blocks 1024..3071 cast X fp32->bf16. grid 3072, 256 thr.
// ---------------------------------------------------------------------------
__global__ __launch_bounds__(256) void prep(
    const float* __restrict__ X,
    const float* __restrict__ w0, const float* __restrict__ w1,
    const float* __restrict__ w2, const float* __restrict__ w3,
    u16* __restrict__ Xb, u16* __restrict__ WT) {
  const int id = blockIdx.x, tid = threadIdx.x;
  if (id >= 1024) {                       // ---- cast X chunk
    size_t base = ((size_t)(id - 1024) * 256 + tid) * 8;
    float4 f0 = *(const float4*)&X[base];
    float4 f1 = *(const float4*)&X[base + 4];
    u16x8 v;
    v[0] = f2bf(f0.x); v[1] = f2bf(f0.y); v[2] = f2bf(f0.z); v[3] = f2bf(f0.w);
    v[4] = f2bf(f1.x); v[5] = f2bf(f1.y); v[6] = f2bf(f1.z); v[7] = f2bf(f1.w);
    *(u16x8*)&Xb[base] = v;
    return;
  }
  // ---- weight transpose tile
  const int z = id >> 8, xy = id & 255, bx = xy & 15, by = xy >> 4;
  const float* in = (z == 0) ? w0 : (z == 1) ? w1 : (z == 2) ? w2 : w3;
  u16* o = WT + (size_t)z * DM * DM;
  __shared__ u16 T[64][65];
  const int n0 = bx * 64, k0 = by * 64;
  #pragma unroll
  for (int i = 0; i < 4; i++) {
    int c = tid + 256 * i, row = c >> 4, col4 = c & 15;
    float4 f = *(const float4*)&in[(size_t)(k0 + row) * DM + n0 + col4 * 4];
    T[row][col4 * 4 + 0] = f2bf(f.x);
    T[row][col4 * 4 + 1] = f2bf(f.y);
    T[row][col4 * 4 + 2] = f2bf(f.z);
    T[row][col4 * 4 + 3] = f2bf(f.w);
  }
  __syncthreads();
  #pragma unroll
  for (int i = 0; i < 2; i++) {
    int c = tid + 256 * i, row = c >> 3, col8 = c & 7;
    u16x8 v;
    #pragma unroll
    for (int e = 0; e < 8; e++) v[e] = T[col8 * 8 + e][row];
    *(u16x8*)&o[(size_t)(n0 + row) * DM + k0 + col8 * 8] = v;
  }
}

// ===========================================================================
// m97-style 128x128 GEMM mainloop (BK=64, global_load_lds 16B, XOR-swizzled
// LDS chunks). A[m][k], Bt[n][k] both bf16. 256 thr, 4 waves in 2x2 (wm,wn).
// LDS: row r (128 B) holds global chunk g at position g^(r&7).
// ===========================================================================
#define GEMM128_MAINLOOP(Aptr, Btptr)                                          \
  __shared__ u16 As[128 * 64];                                                 \
  __shared__ u16 Bs[128 * 64];                                                 \
  const int tid = threadIdx.x, w = tid >> 6, lane = tid & 63;                  \
  const int ml = lane & 15, quad = lane >> 4;                                  \
  const int m0 = blockIdx.y * 128, n0 = blockIdx.x * 128;                      \
  const int wm = w & 1, wn = w >> 1;                                           \
  const int srow = lane >> 3;                 /* 0..7 within 8-row slab */     \
  const int scol = ((lane & 7) ^ srow) * 8;   /* swizzled global chunk */      \
  f32x4 acc[4][4];                                                             \
  _Pragma("unroll") for (int mi = 0; mi < 4; mi++)                             \
    _Pragma("unroll") for (int ni = 0; ni < 4; ni++)                           \
      _Pragma("unroll") for (int e = 0; e < 4; e++) acc[mi][ni][e] = 0.f;      \
  for (int k0 = 0; k0 < DM; k0 += 64) {                                        \
    __syncthreads();                                                           \
    _Pragma("unroll") for (int L = 0; L < 4; L++) {                            \
      int I = w * 4 + L;                                                       \
      gl_lds16(Aptr  + (size_t)(m0 + I * 8 + srow) * DM + k0 + scol,           \
               As + I * 512);                                                  \
      gl_lds16(Btptr + (size_t)(n0 + I * 8 + srow) * DM + k0 + scol,           \
               Bs + I * 512);                                                  \
    }                                                                          \
    __syncthreads();                                                           \
    _Pragma("unroll") for (int kk = 0; kk < 64; kk += 32) {                    \
      const int kc = kk >> 3;                 /* chunk base: 0 or 4 */         \
      short8 am[4], bn[4];                                                     \
      _Pragma("unroll") for (int i = 0; i < 4; i++) {                          \
        int ra = wm * 64 + i * 16 + ml;                                        \
        int rb = wn * 64 + i * 16 + ml;                                        \
        am[i] = *(const short8*)&As[ra * 64 + (((quad + kc) ^ (ra & 7)) * 8)]; \
        bn[i] = *(const short8*)&Bs[rb * 64 + (((quad + kc) ^ (rb & 7)) * 8)]; \
      }                                                                        \
      _Pragma("unroll") for (int mi = 0; mi < 4; mi++)                         \
        _Pragma("unroll") for (int ni = 0; ni < 4; ni++)                       \
          acc[mi][ni] = __builtin_amdgcn_mfma_f32_16x16x32_bf16(               \
              am[mi], bn[ni], acc[mi][ni], 0, 0, 0);                           \
    }                                                                          \
  }

// ---------------------------------------------------------------------------
// QKV GEMM + fused L2 norm: Xb[4096][1024] bf16 @ W. z selects Q/K/V.
// Q,K: per-(head,token) L2-normalized in-register (Q also x1/8), -> [B,H,N,DH].
// V -> transposed [B,H,DH,N] (packed 8B stores). grid (8, 32, 3), 256 thr.
// ---------------------------------------------------------------------------
__global__ __launch_bounds__(256) void gemm_qkv128(
    const u16* __restrict__ Xb, const u16* __restrict__ WT,
    u16* __restrict__ Qo, u16* __restrict__ Ko, u16* __restrict__ Vt) {
  const u16* Bt = WT + (size_t)blockIdx.z * DM * DM;
  GEMM128_MAINLOOP(Xb, Bt)
  const int z = blockIdx.z;
  if (z < 2) {
    u16* OutQK = (z == 0) ? Qo : Ko;
    const float qsc = (z == 0) ? 0.125f : 1.0f;     // fold softmax 1/sqrt(64)
    const int h = (n0 >> 6) + wn;                   // head of this wave's cols
    #pragma unroll
    for (int mi = 0; mi < 4; mi++) {
      int mrow0 = m0 + wm * 64 + mi * 16 + quad * 4;
      int b = mrow0 >> 11, tok0 = mrow0 & (NSEQ - 1);
      #pragma unroll
      for (int r = 0; r < 4; r++) {
        float ss = 0.f;
        #pragma unroll
        for (int ni = 0; ni < 4; ni++) ss += acc[mi][ni][r] * acc[mi][ni][r];
        ss += __shfl_xor(ss, 1, 64);
        ss += __shfl_xor(ss, 2, 64);
        ss += __shfl_xor(ss, 4, 64);
        ss += __shfl_xor(ss, 8, 64);    // sum over the 16 ml lanes (full row)
        float sc = qsc / (sqrtf(ss) + EPS_N);
        #pragma unroll
        for (int ni = 0; ni < 4; ni++)
          OutQK[((size_t)(b * NH + h) * NSEQ + tok0 + r) * DH + ni * 16 + ml] =
              f2bf(acc[mi][ni][r] * sc);
      }
    }
  } else {
    #pragma unroll
    for (int mi = 0; mi < 4; mi++) {
      int mrow0 = m0 + wm * 64 + mi * 16 + quad * 4;
      int b = mrow0 >> 11, tok0 = mrow0 & (NSEQ - 1);
      #pragma unroll
      for (int ni = 0; ni < 4; ni++) {
        int n = n0 + wn * 64 + ni * 16 + ml;
        int h = n >> 6, d = n & 63;
        u16x4 pk;
        #pragma unroll
        for (int r = 0; r < 4; r++) pk[r] = f2bf(acc[mi][ni][r]);
        *(u16x4*)&Vt[((size_t)(b * NH + h) * DH + d) * NSEQ + tok0] = pk;
      }
    }
  }
}

// ---------------------------------------------------------------------------
// Output projection: out = vhat[4096][1024] @ Wo + bo, fp32 out.
// grid (8, 32), 256 thr.
// ---------------------------------------------------------------------------
__global__ __launch_bounds__(256) void gemm_proj128(
    const u16* __restrict__ A, const u16* __restrict__ BtW,
    const float* __restrict__ bias, float* __restrict__ out) {
  GEMM128_MAINLOOP(A, BtW)
  #pragma unroll
  for (int ni = 0; ni < 4; ni++) {
    int n = n0 + wn * 64 + ni * 16 + ml;
    float bz = bias[n];
    #pragma unroll
    for (int mi = 0; mi < 4; mi++) {
      int mrow0 = m0 + wm * 64 + mi * 16 + quad * 4;
      #pragma unroll
      for (int r = 0; r < 4; r++)
        out[(size_t)(mrow0 + r) * DM + n] = acc[mi][ni][r] + bz;
    }
  }
}

// ---------------------------------------------------------------------------
// MFMA flash attention, causal, NO online max (|score|<=0.125 by L2 norm) ->
// O and l are ADDITIVE partials: split keys across waves, combine once/phase.
// Block = 32 q-rows/phase; pair {y, 63-y} -> exactly 33 tile-iters/block.
// Waves: wq = q-half (16 rows), wk = key-half (32 of 64 keys).
// Grid (bh=32, pair=32): XCD = flat%8 = bh%8 -> each XCD touches 4 heads' K/V
// (~3 MB, fits 4 MB L2). 256 thr.
// ---------------------------------------------------------------------------
__global__ __launch_bounds__(256) void flash_attn(
    const u16* __restrict__ Qb, const u16* __restrict__ Kb,
    const u16* __restrict__ Vt, u16* __restrict__ vhat) {
  const int tid = threadIdx.x, w = tid >> 6, lane = tid & 63;
  const int ml = lane & 15, quad = lane >> 4;
  const int wq = w & 1, wk = w >> 1;
  const int bh = blockIdx.x;                  // 0..31 (= b*NH + h)
  const int bb = bh >> 4, hb = bh & 15;
  const int pair = blockIdx.y;                // 0..31
  const u16* Qh = Qb + (size_t)bh * NSEQ * DH;
  const u16* Kh = Kb + (size_t)bh * NSEQ * DH;
  const u16* Vth = Vt + (size_t)bh * DH * NSEQ;

  __shared__ u16 Ks [64][72];      // K[key][d], 144B rows (16B-aligned)
  __shared__ u16 VsT[64][72];      // V^T[d][key]
  __shared__ u16 Ps [4][16][40];   // per-wave P[q16][key32] (C->A transform)
  __shared__ float Os[2][16][66];  // wk0's partial O [wq][q][d]
  __shared__ float Ls[2][16];      // wk0's partial l [wq][q]

  const int vd = tid >> 2, vc = tid & 3;   // V^T staging: row d, chunks vc,vc+4

  for (int ph = 0; ph < 2; ph++) {
    const int qb32 = ph ? (63 - pair) : pair;
    const int q0 = qb32 * 32;
    const int ntiles = (qb32 >> 1) + 1;

    // Q A-frags for this wave's 16 rows: A[m=ml][k=quad*8+j]
    short8 aq[2];
    #pragma unroll
    for (int c = 0; c < 2; c++)
      aq[c] = *(const short8*)&Qh[(size_t)(q0 + wq * 16 + ml) * DH + c * 32 + quad * 8];

    f32x4 oacc[4];
    #pragma unroll
    for (int n = 0; n < 4; n++)
      #pragma unroll
      for (int e = 0; e < 4; e++) oacc[n][e] = 0.f;
    float l_[4] = {0.f, 0.f, 0.f, 0.f};

    for (int t = 0; t < ntiles; t++) {
      const int j0 = t * 64;
      // prefetch K (key=lane, chunks w,w+4) and V^T (row vd, chunks vc,vc+4)
      u16x8 kreg[2], vreg[2];
      #pragma unroll
      for (int i = 0; i < 2; i++) {
        kreg[i] = *(const u16x8*)&Kh[(size_t)(j0 + lane) * DH + (w + 4 * i) * 8];
        vreg[i] = *(const u16x8*)&Vth[(size_t)vd * NSEQ + j0 + (vc + 4 * i) * 8];
      }
      __syncthreads();                       // all waves done with prev tile
      #pragma unroll
      for (int i = 0; i < 2; i++) {
        *(u16x8*)&Ks[lane][(w + 4 * i) * 8] = kreg[i];
        *(u16x8*)&VsT[vd][(vc + 4 * i) * 8] = vreg[i];
      }
      __syncthreads();

      // S (16q x 32k): B-frag = K[key = wk*32 + n*16+ml][d = c*32+quad*8+j]
      f32x4 sacc[2];
      #pragma unroll
      for (int n = 0; n < 2; n++)
        #pragma unroll
        for (int e = 0; e < 4; e++) sacc[n][e] = 0.f;
      #pragma unroll
      for (int c = 0; c < 2; c++)
        #pragma unroll
        for (int n = 0; n < 2; n++) {
          short8 bf = *(const short8*)&Ks[wk * 32 + n * 16 + ml][c * 32 + quad * 8];
          sacc[n] = __builtin_amdgcn_mfma_f32_16x16x32_bf16(aq[c], bf, sacc[n], 0, 0, 0);
        }

      // p = exp(s), causal-masked on the last tile. C-layout: col=ml(key),
      // row=quad*4+r (q).
      const bool lastt = (t == ntiles - 1);
      float p[2][4];
      #pragma unroll
      for (int n = 0; n < 2; n++) {
        int j = j0 + wk * 32 + n * 16 + ml;
        #pragma unroll
        for (int r = 0; r < 4; r++) {
          int q = q0 + wq * 16 + quad * 4 + r;
          float e = __expf(sacc[n][r]);
          p[n][r] = (lastt && j > q) ? 0.f : e;
          l_[r] += p[n][r];
        }
      }

      // P -> per-wave LDS (C->A layout; same-wave ordering via lgkmcnt)
      #pragma unroll
      for (int n = 0; n < 2; n++)
        #pragma unroll
        for (int r = 0; r < 4; r++)
          Ps[w][quad * 4 + r][n * 16 + ml] = f2bf(p[n][r]);

      // O += P·V over this wave's 32 keys: A = P[q=ml][k=quad*8+j],
      // B = V^T[d = n*16+ml][key = wk*32 + quad*8+j]
      short8 ap = *(const short8*)&Ps[w][ml][quad * 8];
      #pragma unroll
      for (int n = 0; n < 4; n++) {
        short8 bv = *(const short8*)&VsT[n * 16 + ml][wk * 32 + quad * 8];
        oacc[n] = __builtin_amdgcn_mfma_f32_16x16x32_bf16(ap, bv, oacc[n], 0, 0, 0);
      }
    }

    // combine the two key-halves (additive: no max rescaling exists)
    float lred[4];
    #pragma unroll
    for (int r = 0; r < 4; r++) {
      float lv = l_[r];
      lv += __shfl_xor(lv, 1, 64);
      lv += __shfl_xor(lv, 2, 64);
      lv += __shfl_xor(lv, 4, 64);
      lv += __shfl_xor(lv, 8, 64);
      lred[r] = lv;                 // per (quad,r): sum over this wave's keys
    }
    if (wk == 0) {
      #pragma unroll
      for (int n = 0; n < 4; n++)
        #pragma unroll
        for (int r = 0; r < 4; r++)
          Os[wq][quad * 4 + r][n * 16 + ml] = oacc[n][r];
      if (ml == 0) {
        #pragma unroll
        for (int r = 0; r < 4; r++) Ls[wq][quad * 4 + r] = lred[r];
      }
    }
    __syncthreads();
    if (wk == 1) {
      #pragma unroll
      for (int r = 0; r < 4; r++) {
        float inv = 1.f / (lred[r] + Ls[wq][quad * 4 + r]);
        int q = q0 + wq * 16 + quad * 4 + r;
        #pragma unroll
        for (int n = 0; n < 4; n++) {
          float o = oacc[n][r] + Os[wq][quad * 4 + r][n * 16 + ml];
          vhat[((size_t)(bb * NSEQ + q)) * DM + hb * DH + n * 16 + ml] =
              f2bf(o * inv);
        }
      }
    }
  }
}

// ---------------------------------------------------------------------------
extern "C" void kernel_launch(void* const* d_in, const int* in_sizes, int n_in,
                              void* d_out, int out_size, void* d_ws, size_t ws_size,
                              hipStream_t stream) {
  const float* X  = (const float*)d_in[0];
  const float* Wq = (const float*)d_in[1];
  const float* Wk = (const float*)d_in[2];
  const float* Wv = (const float*)d_in[3];
  const float* Wo = (const float*)d_in[4];
  const float* bo = (const float*)d_in[5];
  float* out = (float*)d_out;

  // ws (all bf16, 8 MB each): Qb | Kb | Vt[B,H,DH,N] | {Xb then vhat, aliased}
  // | WT (4 transposed weights, 8 MB total) = 40 MB
  const size_t NE = (size_t)BATCH * NSEQ * DM;   // 4,194,304
  u16* Qb   = (u16*)d_ws;
  u16* Kb   = Qb + NE;
  u16* Vt   = Kb + NE;
  u16* XbVh = Vt + NE;                           // Xb / vhat (disjoint lifetimes)
  u16* WT   = XbVh + NE;

  prep        <<<dim3(3072),      256, 0, stream>>>(X, Wq, Wk, Wv, Wo, XbVh, WT);
  gemm_qkv128 <<<dim3(8, 32, 3),  256, 0, stream>>>(XbVh, WT, Qb, Kb, Vt);
  flash_attn  <<<dim3(32, 32),    256, 0, stream>>>(Qb, Kb, Vt, XbVh);
  gemm_proj128<<<dim3(8, 32, 1),  256, 0, stream>>>(XbVh, WT + 3 * (size_t)DM * DM,
                                                    bo, out);
}